// Round 1
// baseline (170.494 us; speedup 1.0000x reference)
//
#include <hip/hip_runtime.h>

// Laplace attention: N=2, C=512, S=256, fp32.
// weights[n,c,d] = softmax_d( -sum_s |k[n,d,s]-q[n,c,s]| / 2 )
// out[n,c,s] = sum_d weights[n,c,d] * v[n,d,s]
//
// Round-5 rewrite: phase 2 (logits) restructured as an L1-distance "GEMM".
//  - No cross-lane reduce in the inner loop: each thread owns a 2c x 2d
//    register tile and accumulates sum_s |k-q| privately over s.
//  - k staged in LDS in s-chunks (natural [d][s] layout, row stride SC+4
//    words == 4 mod 32 -> 2-way bank aliasing only, free on CDNA4).
//  - q tile staged once in LDS (stride S+4, broadcast reads).
//  - k-chunk prefetch into registers overlaps global latency with compute.
//  - LDS: k-chunk aliased with PV partial buffer -> 46 KB, 2 blocks/CU.
//  - __launch_bounds__(256,2): VGPR cap 256, no spill risk.
// Flash-style d-split (DSPLIT=4) + combine kernel kept from round-4.

constexpr int N_ = 2;
constexpr int C_ = 512;
constexpr int S_ = 256;
constexpr int TC = 8;             // q rows per block
constexpr int NW = 4;             // waves per block

// ---- DPP wave-reduce helpers (used only in the small softmax phase) ----
template <int CTRL, int ROW_MASK>
__device__ __forceinline__ float dpp_add(float x) {
    int yi = __builtin_amdgcn_update_dpp(0, __float_as_int(x), CTRL, ROW_MASK, 0xf, true);
    return x + __int_as_float(yi);
}
template <int CTRL, int ROW_MASK>
__device__ __forceinline__ float dpp_max(float x) {
    int yi = __builtin_amdgcn_update_dpp(__float_as_int(x), __float_as_int(x), CTRL, ROW_MASK, 0xf, false);
    return fmaxf(x, __int_as_float(yi));
}
__device__ __forceinline__ float wave_sum_bcast(float x) {
    x = dpp_add<0x111, 0xf>(x);   // row_shr:1
    x = dpp_add<0x112, 0xf>(x);   // row_shr:2
    x = dpp_add<0x114, 0xf>(x);   // row_shr:4
    x = dpp_add<0x118, 0xf>(x);   // row_shr:8
    x = dpp_add<0x142, 0xa>(x);   // row_bcast15
    x = dpp_add<0x143, 0xc>(x);   // row_bcast31 -> lane63 = total
    return __int_as_float(__builtin_amdgcn_readlane(__float_as_int(x), 63));
}
__device__ __forceinline__ float wave_max_bcast(float x) {
    x = dpp_max<0x111, 0xf>(x);
    x = dpp_max<0x112, 0xf>(x);
    x = dpp_max<0x114, 0xf>(x);
    x = dpp_max<0x118, 0xf>(x);
    x = dpp_max<0x142, 0xa>(x);
    x = dpp_max<0x143, 0xc>(x);
    return __int_as_float(__builtin_amdgcn_readlane(__float_as_int(x), 63));
}

template <int DSPLIT>
__global__ __launch_bounds__(256, 2)
void laplace_attn_main(const float* __restrict__ qg,
                       const float* __restrict__ kg,
                       const float* __restrict__ vg,
                       float* __restrict__ ws) {
    constexpr int DH   = C_ / DSPLIT;          // d rows per block (128 / 256)
    constexpr int DPW  = DH / NW;              // d rows per wave  (32 / 64)
    constexpr int DSUB = DPW / 32;             // 32-row groups per wave (1 / 2)
    constexpr int SC   = (DSPLIT >= 4) ? 64 : 32;  // s-chunk
    constexpr int SC4  = SC / 4;
    constexpr int NCH  = S_ / SC;
    constexpr int KST  = SC + 4;               // k row stride: ==4 mod 32, 16B-aligned
    constexpr int QST  = S_ + 4;               // q row stride: ==4 mod 32, 16B-aligned
    constexpr int E    = DH / 64;              // softmax elems per lane
    constexpr int KF4  = DH * SC4 / 256;       // float4 per thread per k-chunk (=8)
    constexpr size_t PO_SZ = (size_t)N_ * C_ * DSPLIT * S_;
    constexpr size_t ST_SZ = (size_t)N_ * C_ * DSPLIT;

    // LDS layout: [ qs | wtT | (ksm aliased with accs) ]
    constexpr int QS_BYTES = TC * QST * 4;
    constexpr int WT_BYTES = DH * TC * 4;
    constexpr int KS_BYTES = DH * KST * 4;
    constexpr int AC_BYTES = NW * TC * (S_ / 4) * 16;
    constexpr int U_BYTES  = (KS_BYTES > AC_BYTES) ? KS_BYTES : AC_BYTES;

    __shared__ __align__(16) char smem_raw[QS_BYTES + WT_BYTES + U_BYTES];
    float  (*qs)[QST]        = (float (*)[QST])smem_raw;
    float  (*wtT)[TC]        = (float (*)[TC])(smem_raw + QS_BYTES);
    float  (*ksm)[KST]       = (float (*)[KST])(smem_raw + QS_BYTES + WT_BYTES);
    float4 (*accs)[TC][S_/4] = (float4 (*)[TC][S_/4])(smem_raw + QS_BYTES + WT_BYTES);

    const int b = blockIdx.x;
    constexpr int per_n = (C_ / TC) * DSPLIT;
    const int n    = b / per_n;
    const int r    = b - n * per_n;
    const int half = r % DSPLIT;
    const int c0   = (r / DSPLIT) * TC;
    const int tid  = threadIdx.x;
    const int w    = tid >> 6;
    const int lane = tid & 63;
    const int cg   = lane >> 4;    // 0..3: c-pair (c = 2cg, 2cg+1)
    const int dg   = lane & 15;    // 0..15: d-slot (d = base + dg + 16j)

    float* po = ws;                   // [N*C][DSPLIT][S]
    float* pm = ws + PO_SZ;           // [N*C][DSPLIT]
    float* pl = pm + ST_SZ;           // [N*C][DSPLIT]

    // ---- stage q tile (all S) ----
    {
        const float* qrow = qg + ((size_t)n * C_ + c0) * S_;
        #pragma unroll
        for (int it = 0; it < 2; ++it) {
            const int f   = tid + 256 * it;        // 0..511 float4 slots
            const int row = f >> 6;                // 64 float4 per row
            const int col = (f & 63) << 2;
            const float4 val = *(const float4*)(qrow + (size_t)row * S_ + col);
            *(float4*)&qs[row][col] = val;
        }
    }

    const float* krow0 = kg + ((size_t)n * C_ + half * DH) * S_;

    // ---- stage k chunk 0 ----
    float4 kreg[KF4];
    #pragma unroll
    for (int it = 0; it < KF4; ++it) {
        const int f   = tid + 256 * it;
        const int row = f / SC4;
        const int col = (f % SC4) << 2;
        kreg[it] = *(const float4*)(krow0 + (size_t)row * S_ + col);
    }
    #pragma unroll
    for (int it = 0; it < KF4; ++it) {
        const int f   = tid + 256 * it;
        const int row = f / SC4;
        const int col = (f % SC4) << 2;
        *(float4*)&ksm[row][col] = kreg[it];
    }
    __syncthreads();

    // ---- phase 2: register-tiled L1-distance accumulation ----
    float acc[2][DSUB][2];
    #pragma unroll
    for (int i = 0; i < 2; ++i)
        #pragma unroll
        for (int sub = 0; sub < DSUB; ++sub)
            #pragma unroll
            for (int j = 0; j < 2; ++j) acc[i][sub][j] = 0.f;

    for (int ch = 0; ch < NCH; ++ch) {
        // prefetch next k-chunk into registers (latency hides under compute)
        if (ch + 1 < NCH) {
            const float* kc = krow0 + (ch + 1) * SC;
            #pragma unroll
            for (int it = 0; it < KF4; ++it) {
                const int f   = tid + 256 * it;
                const int row = f / SC4;
                const int col = (f % SC4) << 2;
                kreg[it] = *(const float4*)(kc + (size_t)row * S_ + col);
            }
        }
        const int sbase = ch * SC;
        #pragma unroll
        for (int t = 0; t < SC4; ++t) {
            const int sl = t << 2;           // chunk-local s
            const int sq = sbase + sl;       // global s (for qs)
            float4 qf0 = *(const float4*)&qs[2 * cg + 0][sq];
            float4 qf1 = *(const float4*)&qs[2 * cg + 1][sq];
            #pragma unroll
            for (int sub = 0; sub < DSUB; ++sub) {
                #pragma unroll
                for (int j = 0; j < 2; ++j) {
                    const int dl = w * DPW + sub * 32 + dg + 16 * j;
                    const float4 kf = *(const float4*)&ksm[dl][sl];
                    acc[0][sub][j] += (fabsf(kf.x - qf0.x) + fabsf(kf.y - qf0.y))
                                    + (fabsf(kf.z - qf0.z) + fabsf(kf.w - qf0.w));
                    acc[1][sub][j] += (fabsf(kf.x - qf1.x) + fabsf(kf.y - qf1.y))
                                    + (fabsf(kf.z - qf1.z) + fabsf(kf.w - qf1.w));
                }
            }
        }
        __syncthreads();                     // done reading ksm
        if (ch + 1 < NCH) {
            #pragma unroll
            for (int it = 0; it < KF4; ++it) {
                const int f   = tid + 256 * it;
                const int row = f / SC4;
                const int col = (f % SC4) << 2;
                *(float4*)&ksm[row][col] = kreg[it];
            }
            __syncthreads();                 // ksm ready for next chunk
        }
    }

    // ---- write logits (transposed: wtT[d][c]) ----
    #pragma unroll
    for (int sub = 0; sub < DSUB; ++sub)
        #pragma unroll
        for (int j = 0; j < 2; ++j) {
            const int dl = w * DPW + sub * 32 + dg + 16 * j;
            wtT[dl][2 * cg + 0] = -0.5f * acc[0][sub][j];
            wtT[dl][2 * cg + 1] = -0.5f * acc[1][sub][j];
        }
    __syncthreads();

    // ---- softmax (partial, unnormalized): wave w handles c = 2w, 2w+1 ----
    #pragma unroll
    for (int cc = 0; cc < 2; ++cc) {
        const int c = 2 * w + cc;
        float x[E];
        #pragma unroll
        for (int e = 0; e < E; ++e) x[e] = wtT[lane + 64 * e][c];
        float m = x[0];
        #pragma unroll
        for (int e = 1; e < E; ++e) m = fmaxf(m, x[e]);
        m = wave_max_bcast(m);
        float l = 0.f;
        #pragma unroll
        for (int e = 0; e < E; ++e) { x[e] = __expf(x[e] - m); l += x[e]; }
        l = wave_sum_bcast(l);
        #pragma unroll
        for (int e = 0; e < E; ++e) wtT[lane + 64 * e][c] = x[e];
        if (lane == 0) {
            const size_t sidx = ((size_t)n * C_ + c0 + c) * DSPLIT + half;
            pm[sidx] = m;
            pl[sidx] = l;
        }
    }
    __syncthreads();   // es ready; also: last read of phase-2 state before accs aliasing

    // ---- phase 4: o_partial[c][s] = sum_d es[c][d] * v[d][s] ----
    float4 oa[TC];
    #pragma unroll
    for (int c = 0; c < TC; ++c) oa[c] = make_float4(0.f, 0.f, 0.f, 0.f);

    const float4* v4 = (const float4*)(vg + ((size_t)n * C_ + half * DH) * S_);
    #pragma unroll 4
    for (int dd = 0; dd < DPW; ++dd) {
        const int dl = w * DPW + dd;
        const float4 vv = v4[(size_t)dl * (S_ / 4) + lane];
        const float4 w0 = *(const float4*)&wtT[dl][0];
        const float4 w1 = *(const float4*)&wtT[dl][4];
        const float wc[TC] = {w0.x, w0.y, w0.z, w0.w, w1.x, w1.y, w1.z, w1.w};
        #pragma unroll
        for (int c = 0; c < TC; ++c) {
            oa[c].x += wc[c] * vv.x; oa[c].y += wc[c] * vv.y;
            oa[c].z += wc[c] * vv.z; oa[c].w += wc[c] * vv.w;
        }
    }
    #pragma unroll
    for (int c = 0; c < TC; ++c) accs[w][c][lane] = oa[c];
    __syncthreads();

    // ---- epilogue: combine 4 waves' partials, write workspace ----
    #pragma unroll
    for (int it = 0; it < 2; ++it) {
        const int slot = tid + 256 * it;       // 0..511 = TC*64
        const int c  = slot >> 6;
        const int ln = slot & 63;
        const float4 a0 = accs[0][c][ln];
        const float4 a1 = accs[1][c][ln];
        const float4 a2 = accs[2][c][ln];
        const float4 a3 = accs[3][c][ln];
        float4 o;
        o.x = (a0.x + a1.x) + (a2.x + a3.x);
        o.y = (a0.y + a1.y) + (a2.y + a3.y);
        o.z = (a0.z + a1.z) + (a2.z + a3.z);
        o.w = (a0.w + a1.w) + (a2.w + a3.w);
        const size_t oidx = (((size_t)n * C_ + c0 + c) * DSPLIT + half) * S_;
        ((float4*)(po + oidx))[ln] = o;
    }
}

template <int DSPLIT>
__global__ __launch_bounds__(64)
void laplace_attn_combine(const float* __restrict__ ws,
                          float* __restrict__ out) {
    constexpr size_t PO_SZ = (size_t)N_ * C_ * DSPLIT * S_;
    constexpr size_t ST_SZ = (size_t)N_ * C_ * DSPLIT;
    const int b    = blockIdx.x;      // (n*C + c)
    const int lane = threadIdx.x;     // s-quad

    const float* po = ws;
    const float* pm = ws + PO_SZ;
    const float* pl = pm + ST_SZ;

    float m[DSPLIT], l[DSPLIT];
    #pragma unroll
    for (int hh = 0; hh < DSPLIT; ++hh) {
        m[hh] = pm[(size_t)b * DSPLIT + hh];
        l[hh] = pl[(size_t)b * DSPLIT + hh];
    }
    float M = m[0];
    #pragma unroll
    for (int hh = 1; hh < DSPLIT; ++hh) M = fmaxf(M, m[hh]);
    float den = 0.f, a[DSPLIT];
    #pragma unroll
    for (int hh = 0; hh < DSPLIT; ++hh) { a[hh] = __expf(m[hh] - M); den += a[hh] * l[hh]; }
    const float inv = 1.f / den;

    float4 rsum = make_float4(0.f, 0.f, 0.f, 0.f);
    #pragma unroll
    for (int hh = 0; hh < DSPLIT; ++hh) {
        const float4 o = ((const float4*)(po + ((size_t)b * DSPLIT + hh) * S_))[lane];
        rsum.x += a[hh] * o.x;
        rsum.y += a[hh] * o.y;
        rsum.z += a[hh] * o.z;
        rsum.w += a[hh] * o.w;
    }
    float4 rr;
    rr.x = rsum.x * inv; rr.y = rsum.y * inv;
    rr.z = rsum.z * inv; rr.w = rsum.w * inv;
    ((float4*)(out + (size_t)b * S_))[lane] = rr;
}

extern "C" void kernel_launch(void* const* d_in, const int* in_sizes, int n_in,
                              void* d_out, int out_size, void* d_ws, size_t ws_size,
                              hipStream_t stream) {
    const float* q = (const float*)d_in[0];
    const float* k = (const float*)d_in[1];
    const float* v = (const float*)d_in[2];
    float* out = (float*)d_out;
    float* ws  = (float*)d_ws;

    constexpr size_t NEED4 =
        ((size_t)N_ * C_ * 4 * S_ + 2 * (size_t)N_ * C_ * 4) * sizeof(float);

    if (ws_size >= NEED4) {
        laplace_attn_main<4><<<dim3(N_ * (C_ / TC) * 4), dim3(256), 0, stream>>>(q, k, v, ws);
        laplace_attn_combine<4><<<dim3(N_ * C_), dim3(64), 0, stream>>>(ws, out);
    } else {
        laplace_attn_main<2><<<dim3(N_ * (C_ / TC) * 2), dim3(256), 0, stream>>>(q, k, v, ws);
        laplace_attn_combine<2><<<dim3(N_ * C_), dim3(64), 0, stream>>>(ws, out);
    }
}

// Round 2
// 164.136 us; speedup vs baseline: 1.0387x; 1.0387x over previous
//
#include <hip/hip_runtime.h>

// Laplace attention: N=2, C=512, S=256, fp32.
// weights[n,c,d] = softmax_d( -sum_s |k[n,d,s]-q[n,c,s]| / 2 )
// out[n,c,s] = sum_d weights[n,c,d] * v[n,d,s]
//
// Round-6 fixes vs round-5 (which ran main at 120us, WRITE_SIZE 267MB):
//  - Rule-#20 scratch bug: phase 4's runtime-indexable `wc[TC]` array sent
//    ~2KB/thread through scratch (the 267MB WRITE / 123MB FETCH anomaly).
//    Rewritten with 8 NAMED float4 accumulators + explicit component FMAs.
//  - XCD-aware mapping: combo=(n,half)=blockIdx.x % 8 pins each k/v panel
//    to one XCD's L2 (round-robin dispatch idiom) -> kills the 512x256KB
//    all-miss k/v re-fetch.
//  - #pragma unroll 8 on the v-loop (more global loads in flight).
// Phase 2 (register-tiled L1-distance GEMM, LDS-staged k chunks) unchanged.
// NOTE: the ~40-45us workspace poison fill is harness-side and inside the
// timed window; controllable budget is main+combine only.

constexpr int N_ = 2;
constexpr int C_ = 512;
constexpr int S_ = 256;
constexpr int TC = 8;             // q rows per block
constexpr int NW = 4;             // waves per block

// ---- DPP wave-reduce helpers (used only in the small softmax phase) ----
template <int CTRL, int ROW_MASK>
__device__ __forceinline__ float dpp_add(float x) {
    int yi = __builtin_amdgcn_update_dpp(0, __float_as_int(x), CTRL, ROW_MASK, 0xf, true);
    return x + __int_as_float(yi);
}
template <int CTRL, int ROW_MASK>
__device__ __forceinline__ float dpp_max(float x) {
    int yi = __builtin_amdgcn_update_dpp(__float_as_int(x), __float_as_int(x), CTRL, ROW_MASK, 0xf, false);
    return fmaxf(x, __int_as_float(yi));
}
__device__ __forceinline__ float wave_sum_bcast(float x) {
    x = dpp_add<0x111, 0xf>(x);   // row_shr:1
    x = dpp_add<0x112, 0xf>(x);   // row_shr:2
    x = dpp_add<0x114, 0xf>(x);   // row_shr:4
    x = dpp_add<0x118, 0xf>(x);   // row_shr:8
    x = dpp_add<0x142, 0xa>(x);   // row_bcast15
    x = dpp_add<0x143, 0xc>(x);   // row_bcast31 -> lane63 = total
    return __int_as_float(__builtin_amdgcn_readlane(__float_as_int(x), 63));
}
__device__ __forceinline__ float wave_max_bcast(float x) {
    x = dpp_max<0x111, 0xf>(x);
    x = dpp_max<0x112, 0xf>(x);
    x = dpp_max<0x114, 0xf>(x);
    x = dpp_max<0x118, 0xf>(x);
    x = dpp_max<0x142, 0xa>(x);
    x = dpp_max<0x143, 0xc>(x);
    return __int_as_float(__builtin_amdgcn_readlane(__float_as_int(x), 63));
}

__device__ __forceinline__ void fma4(float4& a, const float s, const float4& v) {
    a.x += s * v.x; a.y += s * v.y; a.z += s * v.z; a.w += s * v.w;
}

template <int DSPLIT>
__global__ __launch_bounds__(256, 2)
void laplace_attn_main(const float* __restrict__ qg,
                       const float* __restrict__ kg,
                       const float* __restrict__ vg,
                       float* __restrict__ ws) {
    constexpr int DH   = C_ / DSPLIT;          // d rows per block (128 / 256)
    constexpr int DPW  = DH / NW;              // d rows per wave  (32 / 64)
    constexpr int DSUB = DPW / 32;             // 32-row groups per wave (1 / 2)
    constexpr int SC   = (DSPLIT >= 4) ? 64 : 32;  // s-chunk
    constexpr int SC4  = SC / 4;
    constexpr int NCH  = S_ / SC;
    constexpr int KST  = SC + 4;               // k row stride: ==4 mod 32, 16B-aligned
    constexpr int QST  = S_ + 4;               // q row stride: ==4 mod 32, 16B-aligned
    constexpr int E    = DH / 64;              // softmax elems per lane
    constexpr int KF4  = DH * SC4 / 256;       // float4 per thread per k-chunk (=8)
    constexpr size_t PO_SZ = (size_t)N_ * C_ * DSPLIT * S_;
    constexpr size_t ST_SZ = (size_t)N_ * C_ * DSPLIT;

    // LDS layout: [ qs | wtT | (ksm aliased with accs) ]
    constexpr int QS_BYTES = TC * QST * 4;
    constexpr int WT_BYTES = DH * TC * 4;
    constexpr int KS_BYTES = DH * KST * 4;
    constexpr int AC_BYTES = NW * TC * (S_ / 4) * 16;
    constexpr int U_BYTES  = (KS_BYTES > AC_BYTES) ? KS_BYTES : AC_BYTES;

    __shared__ __align__(16) char smem_raw[QS_BYTES + WT_BYTES + U_BYTES];
    float  (*qs)[QST]        = (float (*)[QST])smem_raw;
    float  (*wtT)[TC]        = (float (*)[TC])(smem_raw + QS_BYTES);
    float  (*ksm)[KST]       = (float (*)[KST])(smem_raw + QS_BYTES + WT_BYTES);
    float4 (*accs)[TC][S_/4] = (float4 (*)[TC][S_/4])(smem_raw + QS_BYTES + WT_BYTES);

    // ---- XCD-aware block mapping: combo=(n,half) = blockIdx % (N*DSPLIT) ----
    // Round-robin dispatch sends blocks with the same (b % 8) to the same XCD,
    // so each XCD's L2 caches exactly one k/v panel (DSPLIT=4: 8 combos).
    const int b = blockIdx.x;
    constexpr int per_combo = N_ * DSPLIT;
    const int combo = b % per_combo;
    const int n     = combo / DSPLIT;
    const int half  = combo % DSPLIT;
    const int c0    = (b / per_combo) * TC;
    const int tid  = threadIdx.x;
    const int w    = tid >> 6;
    const int lane = tid & 63;
    const int cg   = lane >> 4;    // 0..3: c-pair (c = 2cg, 2cg+1)
    const int dg   = lane & 15;    // 0..15: d-slot (d = base + dg + 16j)

    float* po = ws;                   // [N*C][DSPLIT][S]
    float* pm = ws + PO_SZ;           // [N*C][DSPLIT]
    float* pl = pm + ST_SZ;           // [N*C][DSPLIT]

    // ---- stage q tile (all S) ----
    {
        const float* qrow = qg + ((size_t)n * C_ + c0) * S_;
        #pragma unroll
        for (int it = 0; it < 2; ++it) {
            const int f   = tid + 256 * it;        // 0..511 float4 slots
            const int row = f >> 6;                // 64 float4 per row
            const int col = (f & 63) << 2;
            const float4 val = *(const float4*)(qrow + (size_t)row * S_ + col);
            *(float4*)&qs[row][col] = val;
        }
    }

    const float* krow0 = kg + ((size_t)n * C_ + half * DH) * S_;

    // ---- stage k chunk 0 ----
    float4 kreg[KF4];
    #pragma unroll
    for (int it = 0; it < KF4; ++it) {
        const int f   = tid + 256 * it;
        const int row = f / SC4;
        const int col = (f % SC4) << 2;
        kreg[it] = *(const float4*)(krow0 + (size_t)row * S_ + col);
    }
    #pragma unroll
    for (int it = 0; it < KF4; ++it) {
        const int f   = tid + 256 * it;
        const int row = f / SC4;
        const int col = (f % SC4) << 2;
        *(float4*)&ksm[row][col] = kreg[it];
    }
    __syncthreads();

    // ---- phase 2: register-tiled L1-distance accumulation ----
    float acc[2][DSUB][2];
    #pragma unroll
    for (int i = 0; i < 2; ++i)
        #pragma unroll
        for (int sub = 0; sub < DSUB; ++sub)
            #pragma unroll
            for (int j = 0; j < 2; ++j) acc[i][sub][j] = 0.f;

    for (int ch = 0; ch < NCH; ++ch) {
        // prefetch next k-chunk into registers (latency hides under compute)
        if (ch + 1 < NCH) {
            const float* kc = krow0 + (ch + 1) * SC;
            #pragma unroll
            for (int it = 0; it < KF4; ++it) {
                const int f   = tid + 256 * it;
                const int row = f / SC4;
                const int col = (f % SC4) << 2;
                kreg[it] = *(const float4*)(kc + (size_t)row * S_ + col);
            }
        }
        const int sbase = ch * SC;
        #pragma unroll
        for (int t = 0; t < SC4; ++t) {
            const int sl = t << 2;           // chunk-local s
            const int sq = sbase + sl;       // global s (for qs)
            float4 qf0 = *(const float4*)&qs[2 * cg + 0][sq];
            float4 qf1 = *(const float4*)&qs[2 * cg + 1][sq];
            #pragma unroll
            for (int sub = 0; sub < DSUB; ++sub) {
                #pragma unroll
                for (int j = 0; j < 2; ++j) {
                    const int dl = w * DPW + sub * 32 + dg + 16 * j;
                    const float4 kf = *(const float4*)&ksm[dl][sl];
                    acc[0][sub][j] += (fabsf(kf.x - qf0.x) + fabsf(kf.y - qf0.y))
                                    + (fabsf(kf.z - qf0.z) + fabsf(kf.w - qf0.w));
                    acc[1][sub][j] += (fabsf(kf.x - qf1.x) + fabsf(kf.y - qf1.y))
                                    + (fabsf(kf.z - qf1.z) + fabsf(kf.w - qf1.w));
                }
            }
        }
        __syncthreads();                     // done reading ksm
        if (ch + 1 < NCH) {
            #pragma unroll
            for (int it = 0; it < KF4; ++it) {
                const int f   = tid + 256 * it;
                const int row = f / SC4;
                const int col = (f % SC4) << 2;
                *(float4*)&ksm[row][col] = kreg[it];
            }
            __syncthreads();                 // ksm ready for next chunk
        }
    }

    // ---- write logits (transposed: wtT[d][c]) ----
    #pragma unroll
    for (int sub = 0; sub < DSUB; ++sub)
        #pragma unroll
        for (int j = 0; j < 2; ++j) {
            const int dl = w * DPW + sub * 32 + dg + 16 * j;
            wtT[dl][2 * cg + 0] = -0.5f * acc[0][sub][j];
            wtT[dl][2 * cg + 1] = -0.5f * acc[1][sub][j];
        }
    __syncthreads();

    // ---- softmax (partial, unnormalized): wave w handles c = 2w, 2w+1 ----
    #pragma unroll
    for (int cc = 0; cc < 2; ++cc) {
        const int c = 2 * w + cc;
        float x[E];
        #pragma unroll
        for (int e = 0; e < E; ++e) x[e] = wtT[lane + 64 * e][c];
        float m = x[0];
        #pragma unroll
        for (int e = 1; e < E; ++e) m = fmaxf(m, x[e]);
        m = wave_max_bcast(m);
        float l = 0.f;
        #pragma unroll
        for (int e = 0; e < E; ++e) { x[e] = __expf(x[e] - m); l += x[e]; }
        l = wave_sum_bcast(l);
        #pragma unroll
        for (int e = 0; e < E; ++e) wtT[lane + 64 * e][c] = x[e];
        if (lane == 0) {
            const size_t sidx = ((size_t)n * C_ + c0 + c) * DSPLIT + half;
            pm[sidx] = m;
            pl[sidx] = l;
        }
    }
    __syncthreads();   // es ready; also: last read of phase-2 state before accs aliasing

    // ---- phase 4: o_partial[c][s] = sum_d es[c][d] * v[d][s] ----
    // 8 NAMED accumulators, all FMAs explicit -> nothing runtime-indexable,
    // nothing the compiler can demote to scratch (rule #20).
    float4 oa0 = make_float4(0.f, 0.f, 0.f, 0.f), oa1 = oa0, oa2 = oa0, oa3 = oa0;
    float4 oa4 = oa0, oa5 = oa0, oa6 = oa0, oa7 = oa0;

    const float4* v4 = (const float4*)(vg + ((size_t)n * C_ + half * DH) * S_);
    #pragma unroll 8
    for (int dd = 0; dd < DPW; ++dd) {
        const int dl = w * DPW + dd;
        const float4 vv = v4[(size_t)dl * (S_ / 4) + lane];
        const float4 w0 = *(const float4*)&wtT[dl][0];
        const float4 w1 = *(const float4*)&wtT[dl][4];
        fma4(oa0, w0.x, vv); fma4(oa1, w0.y, vv);
        fma4(oa2, w0.z, vv); fma4(oa3, w0.w, vv);
        fma4(oa4, w1.x, vv); fma4(oa5, w1.y, vv);
        fma4(oa6, w1.z, vv); fma4(oa7, w1.w, vv);
    }
    accs[w][0][lane] = oa0; accs[w][1][lane] = oa1;
    accs[w][2][lane] = oa2; accs[w][3][lane] = oa3;
    accs[w][4][lane] = oa4; accs[w][5][lane] = oa5;
    accs[w][6][lane] = oa6; accs[w][7][lane] = oa7;
    __syncthreads();

    // ---- epilogue: combine 4 waves' partials, write workspace ----
    // (accs is LDS: runtime indexing here is fine.)
    #pragma unroll
    for (int it = 0; it < 2; ++it) {
        const int slot = tid + 256 * it;       // 0..511 = TC*64
        const int c  = slot >> 6;
        const int ln = slot & 63;
        const float4 a0 = accs[0][c][ln];
        const float4 a1 = accs[1][c][ln];
        const float4 a2 = accs[2][c][ln];
        const float4 a3 = accs[3][c][ln];
        float4 o;
        o.x = (a0.x + a1.x) + (a2.x + a3.x);
        o.y = (a0.y + a1.y) + (a2.y + a3.y);
        o.z = (a0.z + a1.z) + (a2.z + a3.z);
        o.w = (a0.w + a1.w) + (a2.w + a3.w);
        const size_t oidx = (((size_t)n * C_ + c0 + c) * DSPLIT + half) * S_;
        ((float4*)(po + oidx))[ln] = o;
    }
}

template <int DSPLIT>
__global__ __launch_bounds__(64)
void laplace_attn_combine(const float* __restrict__ ws,
                          float* __restrict__ out) {
    constexpr size_t PO_SZ = (size_t)N_ * C_ * DSPLIT * S_;
    constexpr size_t ST_SZ = (size_t)N_ * C_ * DSPLIT;
    const int b    = blockIdx.x;      // (n*C + c)
    const int lane = threadIdx.x;     // s-quad

    const float* po = ws;
    const float* pm = ws + PO_SZ;
    const float* pl = pm + ST_SZ;

    float m[DSPLIT], l[DSPLIT];
    #pragma unroll
    for (int hh = 0; hh < DSPLIT; ++hh) {
        m[hh] = pm[(size_t)b * DSPLIT + hh];
        l[hh] = pl[(size_t)b * DSPLIT + hh];
    }
    float M = m[0];
    #pragma unroll
    for (int hh = 1; hh < DSPLIT; ++hh) M = fmaxf(M, m[hh]);
    float den = 0.f, a[DSPLIT];
    #pragma unroll
    for (int hh = 0; hh < DSPLIT; ++hh) { a[hh] = __expf(m[hh] - M); den += a[hh] * l[hh]; }
    const float inv = 1.f / den;

    float4 rsum = make_float4(0.f, 0.f, 0.f, 0.f);
    #pragma unroll
    for (int hh = 0; hh < DSPLIT; ++hh) {
        const float4 o = ((const float4*)(po + ((size_t)b * DSPLIT + hh) * S_))[lane];
        rsum.x += a[hh] * o.x;
        rsum.y += a[hh] * o.y;
        rsum.z += a[hh] * o.z;
        rsum.w += a[hh] * o.w;
    }
    float4 rr;
    rr.x = rsum.x * inv; rr.y = rsum.y * inv;
    rr.z = rsum.z * inv; rr.w = rsum.w * inv;
    ((float4*)(out + (size_t)b * S_))[lane] = rr;
}

extern "C" void kernel_launch(void* const* d_in, const int* in_sizes, int n_in,
                              void* d_out, int out_size, void* d_ws, size_t ws_size,
                              hipStream_t stream) {
    const float* q = (const float*)d_in[0];
    const float* k = (const float*)d_in[1];
    const float* v = (const float*)d_in[2];
    float* out = (float*)d_out;
    float* ws  = (float*)d_ws;

    constexpr size_t NEED4 =
        ((size_t)N_ * C_ * 4 * S_ + 2 * (size_t)N_ * C_ * 4) * sizeof(float);

    if (ws_size >= NEED4) {
        laplace_attn_main<4><<<dim3(N_ * (C_ / TC) * 4), dim3(256), 0, stream>>>(q, k, v, ws);
        laplace_attn_combine<4><<<dim3(N_ * C_), dim3(64), 0, stream>>>(ws, out);
    } else {
        laplace_attn_main<2><<<dim3(N_ * (C_ / TC) * 2), dim3(256), 0, stream>>>(q, k, v, ws);
        laplace_attn_combine<2><<<dim3(N_ * C_), dim3(64), 0, stream>>>(ws, out);
    }
}